// Round 2
// baseline (117.203 us; speedup 1.0000x reference)
//
#include <hip/hip_runtime.h>

#define CC 256
#define CMM 32
#define KW 7
#define KK 49
#define PADW 3
#define HH 56
#define WW 56
#define HP 62
#define LP 3844   // 62*62
#define LL 3136   // 56*56
#define BB 2
#define MM 8
#define MIDW 16

// ---------------- geometry prior: gpk[cm][i][j], 32*49 floats ----------------
__global__ void gpk_kernel(const float* __restrict__ gp_w1, const float* __restrict__ gp_b1,
                           const float* __restrict__ gp_w2, const float* __restrict__ gp_b2,
                           float* __restrict__ gpk) {
  for (int t = threadIdx.x; t < CMM * KK; t += blockDim.x) {
    int c = t / KK, r = t % KK;
    int i = r / KW, j = r % KW;
    float xp_ = (float)(j - PADW);   // x_pos = a[j] = j-3
    float yp_ = (float)(PADW - i);   // y_pos = 3-i
    float acc = gp_b2[c];
    #pragma unroll
    for (int m = 0; m < MIDW; ++m) {
      float h = gp_w1[m * 2 + 0] * xp_ + gp_w1[m * 2 + 1] * yp_ + gp_b1[m];
      h = fmaxf(h, 0.f);
      acc = fmaf(gp_w2[c * MIDW + m], h, acc);
    }
    gpk[t] = acc;
  }
}

// ---------------- k/q 1x1 conv over the PADDED 62x62 grid ----------------
// Block = 64 padded-pixels x 4 channel-slices (256 threads). Each thread
// accumulates 8 output channels over 64 input channels; slices reduced in LDS.
// Border pixels (zero input) naturally produce bias-only outputs.
__global__ void __launch_bounds__(256) kq_kernel(
    const float* __restrict__ x,
    const float* __restrict__ k_w, const float* __restrict__ k_b,
    const float* __restrict__ q_w, const float* __restrict__ q_b,
    float* __restrict__ km, float* __restrict__ qm) {
  __shared__ float red[4][64][9];           // slice-major, pad 9 vs bank conflicts
  int tid = threadIdx.x;
  int pixi = tid & 63;
  int slice = tid >> 6;                     // 0..3
  int p = blockIdx.x * 64 + pixi;           // padded-grid index
  int g = blockIdx.y;                       // 8 groups of 8 outputs; idx<32 -> k
  int b = blockIdx.z;
  bool valid = (p < LP);
  int py = valid ? p / HP : 0, px = valid ? p % HP : 0;
  bool inb = valid && (py >= PADW && py < PADW + HH && px >= PADW && px < PADW + WW);
  int xo = (py - PADW) * WW + (px - PADW);
  const float* xb = x + (size_t)b * CC * LL + (inb ? xo : 0);
  const float* w0 = (g < 4) ? (k_w + (g * 8) * CC) : (q_w + (g * 8 - CMM) * CC);
  float acc[8];
  #pragma unroll
  for (int u = 0; u < 8; ++u) acc[u] = 0.f;
  int c0 = slice * 64;
  for (int c = c0; c < c0 + 64; ++c) {
    float xv = inb ? xb[(size_t)c * LL] : 0.f;
    #pragma unroll
    for (int u = 0; u < 8; ++u)
      acc[u] = fmaf(w0[u * CC + c], xv, acc[u]);
  }
  #pragma unroll
  for (int u = 0; u < 8; ++u) red[slice][pixi][u] = acc[u];
  __syncthreads();
  if (slice == 0 && valid) {
    #pragma unroll
    for (int u = 0; u < 8; ++u) {
      float s = red[0][pixi][u] + red[1][pixi][u] + red[2][pixi][u] + red[3][pixi][u];
      int idx = g * 8 + u;
      if (idx < CMM) km[((size_t)b * CMM + idx) * LP + p] = s + k_b[idx];
      else           qm[((size_t)b * CMM + (idx - CMM)) * LP + p] = s + q_b[idx - CMM];
    }
  }
}

// ---------------- fused QK * rowwise-softmax * PV ----------------
__global__ void attn_kernel(const float* __restrict__ x,
                            const float* __restrict__ km, const float* __restrict__ qm,
                            const float* __restrict__ gpk, float* __restrict__ pre) {
  int l = blockIdx.x * 256 + threadIdx.x;
  int cm = blockIdx.y;
  int b = blockIdx.z;
  if (l >= LL) return;
  int y = l / WW, xc = l % WW;
  const float* kmb = km + ((size_t)b * CMM + cm) * LP;
  float qc = qm[((size_t)b * CMM + cm) * LP + (y + PADW) * HP + (xc + PADW)];
  const float* gp = gpk + cm * KK;
  const float* xb = x + (size_t)b * CC * LL;
  float acc[MM];
  #pragma unroll
  for (int m = 0; m < MM; ++m) acc[m] = 0.f;
  #pragma unroll
  for (int i = 0; i < KW; ++i) {
    int pyy = y + i;                       // padded row
    const float* krow = kmb + pyy * HP + xc;
    float s[KW];
    float mx = -1e30f;
    #pragma unroll
    for (int j = 0; j < KW; ++j) {
      s[j] = fmaf(krow[j], qc, gp[i * KW + j]);
      mx = fmaxf(mx, s[j]);
    }
    float sum = 0.f;
    #pragma unroll
    for (int j = 0; j < KW; ++j) {
      s[j] = __expf(s[j] - mx);
      sum += s[j];
    }
    float inv = 1.f / sum;
    int iy = pyy - PADW;                   // original image row
    if (iy >= 0 && iy < HH) {
      #pragma unroll
      for (int m = 0; m < MM; ++m) {
        const float* xrow = xb + ((size_t)(m * CMM + cm)) * LL + iy * WW;
        float dot = 0.f;
        #pragma unroll
        for (int j = 0; j < KW; ++j) {
          int ix = xc + j - PADW;
          float xv = (ix >= 0 && ix < WW) ? xrow[ix] : 0.f;
          dot = fmaf(s[j], xv, dot);
        }
        acc[m] = fmaf(dot, inv, acc[m]);
      }
    }
  }
  #pragma unroll
  for (int m = 0; m < MM; ++m)
    pre[((size_t)b * CC + (m * CMM + cm)) * LL + l] = acc[m];
}

// ---------------- final 1x1 conv: out = f_w @ pre + f_b ----------------
// Block = 128 pixels x 2 channel-slices. LDS reduce between slices.
__global__ void __launch_bounds__(256) fconv_kernel(
    const float* __restrict__ pre,
    const float* __restrict__ f_w, const float* __restrict__ f_b,
    float* __restrict__ out) {
  __shared__ float red[128][9];
  int tid = threadIdx.x;
  int pixi = tid & 127;
  int slice = tid >> 7;                    // 0..1
  int l = blockIdx.x * 128 + pixi;
  int og = blockIdx.y;                     // 32 groups of 8 output channels
  int b = blockIdx.z;
  bool valid = (l < LL);
  const float* pb = pre + (size_t)b * CC * LL + (valid ? l : 0);
  const float* w = f_w + (size_t)(og * 8) * CC;
  float acc[8];
  #pragma unroll
  for (int u = 0; u < 8; ++u) acc[u] = 0.f;
  int c0 = slice * 128;
  if (valid) {
    for (int c = c0; c < c0 + 128; ++c) {
      float pv = pb[(size_t)c * LL];
      #pragma unroll
      for (int u = 0; u < 8; ++u)
        acc[u] = fmaf(w[u * CC + c], pv, acc[u]);
    }
  }
  if (slice == 1) {
    #pragma unroll
    for (int u = 0; u < 8; ++u) red[pixi][u] = acc[u];
  }
  __syncthreads();
  if (slice == 0 && valid) {
    float* ob = out + (size_t)b * CC * LL + l;
    #pragma unroll
    for (int u = 0; u < 8; ++u)
      ob[(size_t)(og * 8 + u) * LL] = acc[u] + red[pixi][u] + f_b[og * 8 + u];
  }
}

extern "C" void kernel_launch(void* const* d_in, const int* in_sizes, int n_in,
                              void* d_out, int out_size, void* d_ws, size_t ws_size,
                              hipStream_t stream) {
  const float* x     = (const float*)d_in[0];
  const float* k_w   = (const float*)d_in[1];
  const float* k_b   = (const float*)d_in[2];
  const float* q_w   = (const float*)d_in[3];
  const float* q_b   = (const float*)d_in[4];
  const float* gp_w1 = (const float*)d_in[5];
  const float* gp_b1 = (const float*)d_in[6];
  const float* gp_w2 = (const float*)d_in[7];
  const float* gp_b2 = (const float*)d_in[8];
  const float* f_w   = (const float*)d_in[9];
  const float* f_b   = (const float*)d_in[10];
  float* out = (float*)d_out;

  float* ws  = (float*)d_ws;
  float* gpk = ws;                       // 1568 floats (pad to 2048)
  float* km  = ws + 2048;                // 2*32*3844
  float* qm  = km + (size_t)BB * CMM * LP;
  float* pre = qm + (size_t)BB * CMM * LP;  // 2*256*3136

  hipLaunchKernelGGL(gpk_kernel, dim3(1), dim3(256), 0, stream,
                     gp_w1, gp_b1, gp_w2, gp_b2, gpk);
  hipLaunchKernelGGL(kq_kernel, dim3((LP + 63) / 64, 8, BB), dim3(256), 0, stream,
                     x, k_w, k_b, q_w, q_b, km, qm);
  hipLaunchKernelGGL(attn_kernel, dim3((LL + 255) / 256, CMM, BB), dim3(256), 0, stream,
                     x, km, qm, gpk, pre);
  hipLaunchKernelGGL(fconv_kernel, dim3((LL + 127) / 128, CC / 8, BB), dim3(256), 0, stream,
                     pre, f_w, f_b, out);
}

// Round 3
// 73.483 us; speedup vs baseline: 1.5950x; 1.5950x over previous
//
#include <hip/hip_runtime.h>

#define CC 256
#define CMM 32
#define KW 7
#define KK 49
#define PADW 3
#define HH 56
#define WW 56
#define HP 62
#define LP 3844   // 62*62
#define LL 3136   // 56*56
#define BB 2
#define MM 8
#define MIDW 16

// ---------------- geometry prior: gpk[cm][i][j], 32*49 floats ----------------
__global__ void gpk_kernel(const float* __restrict__ gp_w1, const float* __restrict__ gp_b1,
                           const float* __restrict__ gp_w2, const float* __restrict__ gp_b2,
                           float* __restrict__ gpk) {
  for (int t = threadIdx.x; t < CMM * KK; t += blockDim.x) {
    int c = t / KK, r = t % KK;
    int i = r / KW, j = r % KW;
    float xp_ = (float)(j - PADW);   // x_pos = a[j] = j-3
    float yp_ = (float)(PADW - i);   // y_pos = 3-i
    float acc = gp_b2[c];
    #pragma unroll
    for (int m = 0; m < MIDW; ++m) {
      float h = gp_w1[m * 2 + 0] * xp_ + gp_w1[m * 2 + 1] * yp_ + gp_b1[m];
      h = fmaxf(h, 0.f);
      acc = fmaf(gp_w2[c * MIDW + m], h, acc);
    }
    gpk[t] = acc;
  }
}

// ---------------- k/q 1x1 conv over the PADDED 62x62 grid ----------------
// Block = 64 padded-pixels x 4 channel-slices (256 threads); LDS reduce.
__global__ void __launch_bounds__(256) kq_kernel(
    const float* __restrict__ x,
    const float* __restrict__ k_w, const float* __restrict__ k_b,
    const float* __restrict__ q_w, const float* __restrict__ q_b,
    float* __restrict__ km, float* __restrict__ qm) {
  __shared__ float red[4][64][9];
  int tid = threadIdx.x;
  int pixi = tid & 63;
  int slice = tid >> 6;
  int p = blockIdx.x * 64 + pixi;
  int g = blockIdx.y;
  int b = blockIdx.z;
  bool valid = (p < LP);
  int py = valid ? p / HP : 0, px = valid ? p % HP : 0;
  bool inb = valid && (py >= PADW && py < PADW + HH && px >= PADW && px < PADW + WW);
  int xo = (py - PADW) * WW + (px - PADW);
  const float* xb = x + (size_t)b * CC * LL + (inb ? xo : 0);
  const float* w0 = (g < 4) ? (k_w + (g * 8) * CC) : (q_w + (g * 8 - CMM) * CC);
  float acc[8];
  #pragma unroll
  for (int u = 0; u < 8; ++u) acc[u] = 0.f;
  int c0 = slice * 64;
  for (int c = c0; c < c0 + 64; ++c) {
    float xv = inb ? xb[(size_t)c * LL] : 0.f;
    #pragma unroll
    for (int u = 0; u < 8; ++u)
      acc[u] = fmaf(w0[u * CC + c], xv, acc[u]);
  }
  #pragma unroll
  for (int u = 0; u < 8; ++u) red[slice][pixi][u] = acc[u];
  __syncthreads();
  if (slice == 0 && valid) {
    #pragma unroll
    for (int u = 0; u < 8; ++u) {
      float s = red[0][pixi][u] + red[1][pixi][u] + red[2][pixi][u] + red[3][pixi][u];
      int idx = g * 8 + u;
      if (idx < CMM) km[((size_t)b * CMM + idx) * LP + p] = s + k_b[idx];
      else           qm[((size_t)b * CMM + (idx - CMM)) * LP + p] = s + q_b[idx - CMM];
    }
  }
}

// ---------------- fused QK * rowwise-softmax * PV ----------------
__global__ void attn_kernel(const float* __restrict__ x,
                            const float* __restrict__ km, const float* __restrict__ qm,
                            const float* __restrict__ gpk, float* __restrict__ pre) {
  int l = blockIdx.x * 256 + threadIdx.x;
  int cm = blockIdx.y;
  int b = blockIdx.z;
  if (l >= LL) return;
  int y = l / WW, xc = l % WW;
  const float* kmb = km + ((size_t)b * CMM + cm) * LP;
  float qc = qm[((size_t)b * CMM + cm) * LP + (y + PADW) * HP + (xc + PADW)];
  const float* gp = gpk + cm * KK;
  const float* xb = x + (size_t)b * CC * LL;
  float acc[MM];
  #pragma unroll
  for (int m = 0; m < MM; ++m) acc[m] = 0.f;
  #pragma unroll
  for (int i = 0; i < KW; ++i) {
    int pyy = y + i;
    const float* krow = kmb + pyy * HP + xc;
    float s[KW];
    float mx = -1e30f;
    #pragma unroll
    for (int j = 0; j < KW; ++j) {
      s[j] = fmaf(krow[j], qc, gp[i * KW + j]);
      mx = fmaxf(mx, s[j]);
    }
    float sum = 0.f;
    #pragma unroll
    for (int j = 0; j < KW; ++j) {
      s[j] = __expf(s[j] - mx);
      sum += s[j];
    }
    float inv = 1.f / sum;
    int iy = pyy - PADW;
    if (iy >= 0 && iy < HH) {
      #pragma unroll
      for (int m = 0; m < MM; ++m) {
        const float* xrow = xb + ((size_t)(m * CMM + cm)) * LL + iy * WW;
        float dot = 0.f;
        #pragma unroll
        for (int j = 0; j < KW; ++j) {
          int ix = xc + j - PADW;
          float xv = (ix >= 0 && ix < WW) ? xrow[ix] : 0.f;
          dot = fmaf(s[j], xv, dot);
        }
        acc[m] = fmaf(dot, inv, acc[m]);
      }
    }
  }
  #pragma unroll
  for (int m = 0; m < MM; ++m)
    pre[((size_t)b * CC + (m * CMM + cm)) * LL + l] = acc[m];
}

// ---------------- final 1x1 conv as LDS-tiled f32 GEMM ----------------
// out[oc][l] = sum_k f_w[oc][k] * pre[k][l] + f_b[oc]
// Block: 64 oc x 64 px, 256 threads, micro-tile 4x4, K staged in chunks of 64.
#define KC 64
__global__ void __launch_bounds__(256) fconv_kernel(
    const float* __restrict__ pre,
    const float* __restrict__ f_w, const float* __restrict__ f_b,
    float* __restrict__ out) {
  __shared__ float wT[KC][68];   // [k][oc] (transposed) -> b128 fragment reads
  __shared__ float pT[KC][68];   // [k][px]
  int tid = threadIdx.x;
  int l0 = blockIdx.x * 64;
  int oc0 = blockIdx.y * 64;
  int b = blockIdx.z;
  int tx = tid & 15;             // px group (4 px)
  int ty = tid >> 4;             // oc group (4 oc)
  float acc[4][4];
  #pragma unroll
  for (int r = 0; r < 4; ++r)
    #pragma unroll
    for (int c = 0; c < 4; ++c) acc[r][c] = 0.f;

  int s_oc = tid >> 2;           // staging: one oc row / k row per 4 threads
  int s_k4 = (tid & 3) * 16;

  for (int kc = 0; kc < CC; kc += KC) {
    // stage weights transposed: wT[k][oc] <- f_w[oc0+s_oc][kc + s_k4 + ...]
    const float* wrow = f_w + (size_t)(oc0 + s_oc) * CC + kc + s_k4;
    #pragma unroll
    for (int i = 0; i < 4; ++i) {
      float4 wv = *(const float4*)(wrow + i * 4);
      wT[s_k4 + i * 4 + 0][s_oc] = wv.x;
      wT[s_k4 + i * 4 + 1][s_oc] = wv.y;
      wT[s_k4 + i * 4 + 2][s_oc] = wv.z;
      wT[s_k4 + i * 4 + 3][s_oc] = wv.w;
    }
    // stage pre: pT[k][px] <- pre[b][kc+s_oc][l0 + s_k4 + ...]
    const float* prow = pre + ((size_t)b * CC + kc + s_oc) * LL + l0 + s_k4;
    #pragma unroll
    for (int i = 0; i < 4; ++i) {
      float4 pv = *(const float4*)(prow + i * 4);
      *(float4*)&pT[s_oc][s_k4 + i * 4] = pv;
    }
    __syncthreads();
    #pragma unroll 8
    for (int k = 0; k < KC; ++k) {
      float4 wv = *(const float4*)&wT[k][ty * 4];
      float4 pv = *(const float4*)&pT[k][tx * 4];
      const float wr[4] = {wv.x, wv.y, wv.z, wv.w};
      const float pc[4] = {pv.x, pv.y, pv.z, pv.w};
      #pragma unroll
      for (int r = 0; r < 4; ++r)
        #pragma unroll
        for (int c = 0; c < 4; ++c)
          acc[r][c] = fmaf(wr[r], pc[c], acc[r][c]);
    }
    __syncthreads();
  }
  #pragma unroll
  for (int r = 0; r < 4; ++r) {
    int oc = oc0 + ty * 4 + r;
    float bias = f_b[oc];
    float4 o;
    o.x = acc[r][0] + bias;
    o.y = acc[r][1] + bias;
    o.z = acc[r][2] + bias;
    o.w = acc[r][3] + bias;
    *(float4*)&out[((size_t)b * CC + oc) * LL + l0 + tx * 4] = o;
  }
}

extern "C" void kernel_launch(void* const* d_in, const int* in_sizes, int n_in,
                              void* d_out, int out_size, void* d_ws, size_t ws_size,
                              hipStream_t stream) {
  const float* x     = (const float*)d_in[0];
  const float* k_w   = (const float*)d_in[1];
  const float* k_b   = (const float*)d_in[2];
  const float* q_w   = (const float*)d_in[3];
  const float* q_b   = (const float*)d_in[4];
  const float* gp_w1 = (const float*)d_in[5];
  const float* gp_b1 = (const float*)d_in[6];
  const float* gp_w2 = (const float*)d_in[7];
  const float* gp_b2 = (const float*)d_in[8];
  const float* f_w   = (const float*)d_in[9];
  const float* f_b   = (const float*)d_in[10];
  float* out = (float*)d_out;

  float* ws  = (float*)d_ws;
  float* gpk = ws;                       // 1568 floats (pad to 2048)
  float* km  = ws + 2048;                // 2*32*3844
  float* qm  = km + (size_t)BB * CMM * LP;
  float* pre = qm + (size_t)BB * CMM * LP;  // 2*256*3136

  hipLaunchKernelGGL(gpk_kernel, dim3(1), dim3(256), 0, stream,
                     gp_w1, gp_b1, gp_w2, gp_b2, gpk);
  hipLaunchKernelGGL(kq_kernel, dim3((LP + 63) / 64, 8, BB), dim3(256), 0, stream,
                     x, k_w, k_b, q_w, q_b, km, qm);
  hipLaunchKernelGGL(attn_kernel, dim3((LL + 255) / 256, CMM, BB), dim3(256), 0, stream,
                     x, km, qm, gpk, pre);
  hipLaunchKernelGGL(fconv_kernel, dim3(LL / 64, CC / 64, BB), dim3(256), 0, stream,
                     pre, f_w, f_b, out);
}

// Round 4
// 56.017 us; speedup vs baseline: 2.0923x; 1.3118x over previous
//
#include <hip/hip_runtime.h>
#include <hip/hip_bf16.h>

#define CC 256
#define CMM 32
#define KW 7
#define KK 49
#define PADW 3
#define HH 56
#define WW 56
#define HP 62
#define LP 3844   // 62*62
#define LL 3136   // 56*56
#define BB 2
#define MM 8
#define MIDW 16

typedef __attribute__((ext_vector_type(8))) short bf16x8;
typedef __attribute__((ext_vector_type(4))) float f32x4;

__device__ inline short bfr(float f) {   // f32 -> bf16 bits, round-to-nearest-even
  unsigned int u = __builtin_bit_cast(unsigned int, f);
  u += 0x7fffu + ((u >> 16) & 1u);
  return (short)(u >> 16);
}

// ---------------- geometry prior: gpk[cm][i][j], 32*49 floats ----------------
__global__ void gpk_kernel(const float* __restrict__ gp_w1, const float* __restrict__ gp_b1,
                           const float* __restrict__ gp_w2, const float* __restrict__ gp_b2,
                           float* __restrict__ gpk) {
  for (int t = threadIdx.x; t < CMM * KK; t += blockDim.x) {
    int c = t / KK, r = t % KK;
    int i = r / KW, j = r % KW;
    float xp_ = (float)(j - PADW);
    float yp_ = (float)(PADW - i);
    float acc = gp_b2[c];
    #pragma unroll
    for (int m = 0; m < MIDW; ++m) {
      float h = gp_w1[m * 2 + 0] * xp_ + gp_w1[m * 2 + 1] * yp_ + gp_b1[m];
      h = fmaxf(h, 0.f);
      acc = fmaf(gp_w2[c * MIDW + m], h, acc);
    }
    gpk[t] = acc;
  }
}

// ---------------- k/q 1x1 conv over the PADDED 62x62 grid ----------------
__global__ void __launch_bounds__(256) kq_kernel(
    const float* __restrict__ x,
    const float* __restrict__ k_w, const float* __restrict__ k_b,
    const float* __restrict__ q_w, const float* __restrict__ q_b,
    float* __restrict__ km, float* __restrict__ qm) {
  __shared__ float red[4][64][9];
  int tid = threadIdx.x;
  int pixi = tid & 63;
  int slice = tid >> 6;
  int p = blockIdx.x * 64 + pixi;
  int g = blockIdx.y;
  int b = blockIdx.z;
  bool valid = (p < LP);
  int py = valid ? p / HP : 0, px = valid ? p % HP : 0;
  bool inb = valid && (py >= PADW && py < PADW + HH && px >= PADW && px < PADW + WW);
  int xo = (py - PADW) * WW + (px - PADW);
  const float* xb = x + (size_t)b * CC * LL + (inb ? xo : 0);
  const float* w0 = (g < 4) ? (k_w + (g * 8) * CC) : (q_w + (g * 8 - CMM) * CC);
  float acc[8];
  #pragma unroll
  for (int u = 0; u < 8; ++u) acc[u] = 0.f;
  int c0 = slice * 64;
  for (int c = c0; c < c0 + 64; ++c) {
    float xv = inb ? xb[(size_t)c * LL] : 0.f;
    #pragma unroll
    for (int u = 0; u < 8; ++u)
      acc[u] = fmaf(w0[u * CC + c], xv, acc[u]);
  }
  #pragma unroll
  for (int u = 0; u < 8; ++u) red[slice][pixi][u] = acc[u];
  __syncthreads();
  if (slice == 0 && valid) {
    #pragma unroll
    for (int u = 0; u < 8; ++u) {
      float s = red[0][pixi][u] + red[1][pixi][u] + red[2][pixi][u] + red[3][pixi][u];
      int idx = g * 8 + u;
      if (idx < CMM) km[((size_t)b * CMM + idx) * LP + p] = s + k_b[idx];
      else           qm[((size_t)b * CMM + (idx - CMM)) * LP + p] = s + q_b[idx - CMM];
    }
  }
}

// ---------------- fused QK * rowwise-softmax * PV, LDS-tiled ----------------
// Block: 4 output rows x 56 cols, one cm, one b. Grid (14, 32, 2).
// x tile split into two [10][64][4] halves so window reads are ds_read_b128
// at 16B stride (conflict-free). Zero-padded borders: no bounds checks inside.
__global__ void __launch_bounds__(256) attn_kernel(
    const float* __restrict__ x, const float* __restrict__ km,
    const float* __restrict__ qm, const float* __restrict__ gpk,
    __hip_bfloat16* __restrict__ pre) {
  __shared__ float xs[2][10][64][4];   // [m-half][row][col][m%4]
  __shared__ float ks[10][64];
  __shared__ float gs[KK];
  int t = threadIdx.x;
  int band = blockIdx.x;               // 0..13  (4 rows each)
  int cm = blockIdx.y;
  int b = blockIdx.z;
  int y0 = band * 4;

  if (t < KK) gs[t] = gpk[cm * KK + t];
  const float* kmb = km + ((size_t)b * CMM + cm) * LP;
  for (int e = t; e < 640; e += 256) {
    int ri = e >> 6, cl = e & 63;
    ks[ri][cl] = (cl < HP) ? kmb[(y0 + ri) * HP + cl] : 0.f;
  }
  const float* xg = x + ((size_t)b * CC) * LL;
  for (int cell = t; cell < 640; cell += 256) {
    int ri = cell >> 6, cl = cell & 63;
    int ir = y0 - PADW + ri;
    int ic = cl - PADW;
    bool ok = (ir >= 0 && ir < HH && ic >= 0 && ic < WW);
    float v[8];
    #pragma unroll
    for (int m = 0; m < 8; ++m)
      v[m] = ok ? xg[((size_t)(m * CMM + cm)) * LL + ir * WW + ic] : 0.f;
    f32x4 lo = {v[0], v[1], v[2], v[3]};
    f32x4 hi = {v[4], v[5], v[6], v[7]};
    *(f32x4*)&xs[0][ri][cl][0] = lo;
    *(f32x4*)&xs[1][ri][cl][0] = hi;
  }
  __syncthreads();

  int r = t >> 6, c = t & 63;
  bool act = (c < WW);
  int ce = act ? c : 0;
  float qc = act ? qm[((size_t)b * CMM + cm) * LP + (y0 + r + PADW) * HP + (c + PADW)]
                 : 0.f;
  float acc[8];
  #pragma unroll
  for (int m = 0; m < 8; ++m) acc[m] = 0.f;

  #pragma unroll
  for (int i = 0; i < KW; ++i) {
    int row = r + i;
    float sv[KW];
    #pragma unroll
    for (int j = 0; j < KW; ++j)
      sv[j] = fmaf(ks[row][ce + j], qc, gs[i * KW + j]);
    float mx = fmaxf(fmaxf(fmaxf(sv[0], sv[1]), fmaxf(sv[2], sv[3])),
                     fmaxf(fmaxf(sv[4], sv[5]), sv[6]));
    float sum = 0.f;
    #pragma unroll
    for (int j = 0; j < KW; ++j) { sv[j] = __expf(sv[j] - mx); sum += sv[j]; }
    float inv = __builtin_amdgcn_rcpf(sum);
    #pragma unroll
    for (int j = 0; j < KW; ++j) {
      float wgt = sv[j] * inv;
      f32x4 xa = *(const f32x4*)&xs[0][row][ce + j][0];
      f32x4 xb = *(const f32x4*)&xs[1][row][ce + j][0];
      #pragma unroll
      for (int m = 0; m < 4; ++m) {
        acc[m]     = fmaf(wgt, xa[m], acc[m]);
        acc[m + 4] = fmaf(wgt, xb[m], acc[m + 4]);
      }
    }
  }
  if (act) {
    #pragma unroll
    for (int m = 0; m < 8; ++m)
      pre[((size_t)b * CC + (m * CMM + cm)) * LL + (y0 + r) * WW + c] =
          __float2bfloat16(acc[m]);
  }
}

// ---------------- final 1x1 conv: bf16 MFMA GEMM, no LDS ----------------
// out[oc][l] = sum_k f_w[oc][k] * pre[k][l] + f_b[oc]
// Block: 64 oc x 64 px, 4 waves; wave w owns 16 oc rows. A-frags preloaded
// (f_w cvt'd to bf16 in-reg); B-frags read straight from global (L1/L2-hot).
__global__ void __launch_bounds__(256) fconv_kernel(
    const unsigned short* __restrict__ preb,
    const float* __restrict__ f_w, const float* __restrict__ f_b,
    float* __restrict__ out) {
  int t = threadIdx.x;
  int lane = t & 63;
  int w = t >> 6;
  int px0 = blockIdx.x * 64;
  int oc0 = blockIdx.y * 64;
  int b = blockIdx.z;
  int l15 = lane & 15;
  int hi = lane >> 4;

  // A-frags: af[s][j] = bf16(f_w[oc0+w*16+l15][s*32 + hi*8 + j])
  bf16x8 af[8];
  const float* wrow = f_w + (size_t)(oc0 + w * 16 + l15) * CC + hi * 8;
  #pragma unroll
  for (int s = 0; s < 8; ++s) {
    f32x4 w0 = *(const f32x4*)(wrow + s * 32);
    f32x4 w1 = *(const f32x4*)(wrow + s * 32 + 4);
    bf16x8 a;
    #pragma unroll
    for (int j = 0; j < 4; ++j) { a[j] = bfr(w0[j]); a[j + 4] = bfr(w1[j]); }
    af[s] = a;
  }

  f32x4 acc[4];
  #pragma unroll
  for (int q = 0; q < 4; ++q) acc[q] = {0.f, 0.f, 0.f, 0.f};

  const unsigned short* pb = preb + ((size_t)b * CC) * LL + px0 + l15;
  #pragma unroll
  for (int s = 0; s < 8; ++s) {
    #pragma unroll
    for (int q = 0; q < 4; ++q) {
      bf16x8 bv;
      #pragma unroll
      for (int j = 0; j < 8; ++j)
        bv[j] = (short)pb[(size_t)(s * 32 + hi * 8 + j) * LL + q * 16];
      acc[q] = __builtin_amdgcn_mfma_f32_16x16x32_bf16(af[s], bv, acc[q], 0, 0, 0);
    }
  }

  #pragma unroll
  for (int q = 0; q < 4; ++q) {
    #pragma unroll
    for (int rr = 0; rr < 4; ++rr) {
      int oc = oc0 + w * 16 + hi * 4 + rr;
      out[((size_t)b * CC + oc) * LL + px0 + q * 16 + l15] = acc[q][rr] + f_b[oc];
    }
  }
}

extern "C" void kernel_launch(void* const* d_in, const int* in_sizes, int n_in,
                              void* d_out, int out_size, void* d_ws, size_t ws_size,
                              hipStream_t stream) {
  const float* x     = (const float*)d_in[0];
  const float* k_w   = (const float*)d_in[1];
  const float* k_b   = (const float*)d_in[2];
  const float* q_w   = (const float*)d_in[3];
  const float* q_b   = (const float*)d_in[4];
  const float* gp_w1 = (const float*)d_in[5];
  const float* gp_b1 = (const float*)d_in[6];
  const float* gp_w2 = (const float*)d_in[7];
  const float* gp_b2 = (const float*)d_in[8];
  const float* f_w   = (const float*)d_in[9];
  const float* f_b   = (const float*)d_in[10];
  float* out = (float*)d_out;

  float* ws  = (float*)d_ws;
  float* gpk = ws;                                  // 2048 floats reserved
  float* km  = ws + 2048;                           // 2*32*3844
  float* qm  = km + (size_t)BB * CMM * LP;
  __hip_bfloat16* pre = (__hip_bfloat16*)(qm + (size_t)BB * CMM * LP);  // 2*256*3136 bf16

  hipLaunchKernelGGL(gpk_kernel, dim3(1), dim3(256), 0, stream,
                     gp_w1, gp_b1, gp_w2, gp_b2, gpk);
  hipLaunchKernelGGL(kq_kernel, dim3((LP + 63) / 64, 8, BB), dim3(256), 0, stream,
                     x, k_w, k_b, q_w, q_b, km, qm);
  hipLaunchKernelGGL(attn_kernel, dim3(HH / 4, CMM, BB), dim3(256), 0, stream,
                     x, km, qm, gpk, pre);
  hipLaunchKernelGGL(fconv_kernel, dim3(LL / 64, CC / 64, BB), dim3(256), 0, stream,
                     (const unsigned short*)pre, f_w, f_b, out);
}